// Round 6
// baseline (403.278 us; speedup 1.0000x reference)
//
#include <hip/hip_runtime.h>

// R13: attn key-split. Grid (32,16,2): blockIdx.z owns 1024 keys -> 4096
// waves (16/CU, 4/SIMD) at w_q=32 -- the combination R10 (4/SIMD, w_q=16)
// and R12 (2/SIMD, w_q=32) each half-had. K-only LDS dbuf (32 KB); V read
// DIRECT from L2 (swizzle-cancel address, verified R9/R12 algebra). Blocks
// write unnormalized partial O (z=0 -> d_out, z=1 -> ws over dead Wt/Xbv)
// + per-(h,q) partial l; ln fuses the combine (per-head l scale per 64-dh
// segment) + qmask + residual + LayerNorm. attn sheds the queries read.
// T5 setprio around the MFMA/softmax cluster. Barriers/block: 16 -> 8.

typedef __attribute__((ext_vector_type(8))) __bf16 bf16x8;
typedef __attribute__((ext_vector_type(4))) float f32x4;

#if __has_builtin(__builtin_amdgcn_exp2f)
#define EXP2F __builtin_amdgcn_exp2f
#else
#define EXP2F exp2f
#endif

#define QSCALE (0.125f * 1.4426950408889634f)  // fold /sqrt(64) and ln->log2

__device__ __forceinline__ unsigned short f2bf(float f) {
  return __builtin_bit_cast(unsigned short, (__bf16)f);
}
__device__ __forceinline__ unsigned pk2(float a, float b) {
  return (unsigned)f2bf(a) | ((unsigned)f2bf(b) << 16);
}
__device__ __forceinline__ f32x4 mfma16(bf16x8 a, bf16x8 b, f32x4 c) {
  return __builtin_amdgcn_mfma_f32_16x16x32_bf16(a, b, c, 0, 0, 0);
}
__device__ __forceinline__ bf16x8 ld_bf8(const unsigned short* p) {
  return *(const bf16x8*)p;
}
// async global->LDS, 16 B per lane; LDS dst is wave-uniform base + lane*16
__device__ __forceinline__ void g2l16(const void* g, void* l) {
  __builtin_amdgcn_global_load_lds(
      (const __attribute__((address_space(1))) void*)g,
      (__attribute__((address_space(3))) void*)l, 16, 0, 0);
}

// ---------------------------------------------------------------------------
// Kernel 1: transpose + convert the three 512x512 weight matrices to bf16,
// layout Wt[z][n][k] (n-major) so MFMA B-fragments read contiguous k.
// ---------------------------------------------------------------------------
__global__ __launch_bounds__(256) void wt_kernel(const float* __restrict__ Wq,
                                                 const float* __restrict__ Wk,
                                                 const float* __restrict__ Wv,
                                                 unsigned short* __restrict__ Wt) {
  int idx = blockIdx.x * 256 + threadIdx.x;
  int o = idx * 8;
  int z = o >> 18;
  int rem = o & 262143;
  int n = rem >> 9;
  int k0 = rem & 511;
  const float* W = (z == 0) ? Wq : ((z == 1) ? Wk : Wv);
  unsigned int w[4];
#pragma unroll
  for (int i = 0; i < 4; ++i) {
    unsigned short lo = f2bf(W[(k0 + 2 * i) * 512 + n]);
    unsigned short hi = f2bf(W[(k0 + 2 * i + 1) * 512 + n]);
    w[i] = (unsigned)lo | ((unsigned)hi << 16);
  }
  *(uint4*)(Wt + o) = make_uint4(w[0], w[1], w[2], w[3]);
}

// ---------------------------------------------------------------------------
// Kernel 1b: convert X (queries/keys/values) fp32->bf16 rows, and compute
// the padding masks from exact fp32 row sums: qmask (0/1, multiplicative)
// and kbias (0/-1e30, folded into the QK MFMA accumulator init).
// One wave per 512-float row; 6144 blocks x 4 rows.
// ---------------------------------------------------------------------------
__global__ __launch_bounds__(256) void xcvt_kernel(
    const float* __restrict__ Xq, const float* __restrict__ Xk,
    const float* __restrict__ Xv, unsigned short* __restrict__ Xbq,
    unsigned short* __restrict__ Xbk, unsigned short* __restrict__ Xbv,
    float* __restrict__ qmask, float* __restrict__ kbias) {
  int row = blockIdx.x * 4 + (threadIdx.x >> 6);
  int lane = threadIdx.x & 63;
  int z = row >> 13;
  int r = row & 8191;
  const float* X = (z == 0) ? Xq : ((z == 1) ? Xk : Xv);
  unsigned short* Xb = (z == 0) ? Xbq : ((z == 1) ? Xbk : Xbv);
  const float* p = X + r * 512 + lane * 8;
  f32x4 lo = *(const f32x4*)p;
  f32x4 hi = *(const f32x4*)(p + 4);
  *(uint4*)(Xb + r * 512 + lane * 8) =
      make_uint4(pk2(lo[0], lo[1]), pk2(lo[2], lo[3]), pk2(hi[0], hi[1]),
                 pk2(hi[2], hi[3]));
  if (z < 2) {
    float s = lo[0] + lo[1] + lo[2] + lo[3] + hi[0] + hi[1] + hi[2] + hi[3];
#pragma unroll
    for (int off = 1; off < 64; off <<= 1) s += __shfl_xor(s, off);
    if (lane == 0) {
      if (z == 0)
        qmask[r] = (s == 0.f) ? 0.f : 1.f;
      else
        kbias[r] = (s == 0.f) ? -1.0e30f : 0.f;
    }
  }
}

// ---------------------------------------------------------------------------
// Kernel 2: QKV projection, pure-bf16 double-buffered GEMM, ONE barrier per
// K-step. A and B staged [128][32] shorts with source-side XOR swizzle.
// Grid (192 m-blocks, 4 n-blocks); z = m-block/64. Tile 128x128, BK=32.
// V stored transposed with the permuted intra-32-key order
// (pos = quad*8 + sub*4 + r), matching attn's P register-repack k-order.
// ---------------------------------------------------------------------------
__global__ __launch_bounds__(256, 3) void proj_kernel(
    const unsigned short* __restrict__ Xbq, const unsigned short* __restrict__ Xbk,
    const unsigned short* __restrict__ Xbv, const float* __restrict__ bq,
    const float* __restrict__ bk, const float* __restrict__ bv,
    const unsigned short* __restrict__ Wt, unsigned short* __restrict__ Qb,
    unsigned short* __restrict__ Kb, unsigned short* __restrict__ Vt) {
  __shared__ unsigned short Asm[2][128][32];
  __shared__ unsigned short Bsm[2][128][32];

  int tid = threadIdx.x;
  int m0g = blockIdx.x * 128;
  int z = m0g >> 13;
  int m0 = m0g & 8191;
  int n0 = blockIdx.y * 128;
  const unsigned short* Xb = (z == 0) ? Xbq : ((z == 1) ? Xbk : Xbv);
  const float* bias = (z == 0) ? bq : ((z == 1) ? bk : bv);
  const unsigned short* Wz = Wt + z * 262144;

  int w = tid >> 6, lane = tid & 63;
  int wm = w >> 1, wn = w & 1;
  int mrow = lane & 15, quad = lane >> 4;

  int srow = tid >> 2, sslot = tid & 3;
  int sxs = sslot ^ ((srow >> 1) & 3);
  const unsigned short* gA = Xb + (m0 + srow) * 512 + sxs * 8;
  const unsigned short* gB = Wz + (n0 + srow) * 512 + sxs * 8;
  char* lA = (char*)&Asm[0][0][0] + tid * 16;
  char* lB = (char*)&Bsm[0][0][0] + tid * 16;

  int rs = (quad ^ ((mrow >> 1) & 3)) * 8;

  f32x4 zero = {0.f, 0.f, 0.f, 0.f};
  f32x4 acc[4][4];
#pragma unroll
  for (int i = 0; i < 4; ++i)
#pragma unroll
    for (int j = 0; j < 4; ++j) acc[i][j] = zero;

  g2l16(gA, lA);
  g2l16(gA + 64 * 512, lA + 4096);
  g2l16(gB, lB);
  g2l16(gB + 64 * 512, lB + 4096);
  __syncthreads();

  for (int kc = 0; kc < 16; ++kc) {
    int cur = kc & 1;
    if (kc < 15) {
      int ko = (kc + 1) * 32;
      int nb = cur ^ 1;
      g2l16(gA + ko, lA + nb * 8192);
      g2l16(gA + ko + 64 * 512, lA + nb * 8192 + 4096);
      g2l16(gB + ko, lB + nb * 8192);
      g2l16(gB + ko + 64 * 512, lB + nb * 8192 + 4096);
    }
    bf16x8 af[4], bfr[4];
#pragma unroll
    for (int mt = 0; mt < 4; ++mt)
      af[mt] = ld_bf8(&Asm[cur][wm * 64 + mt * 16 + mrow][rs]);
#pragma unroll
    for (int nt = 0; nt < 4; ++nt)
      bfr[nt] = ld_bf8(&Bsm[cur][wn * 64 + nt * 16 + mrow][rs]);
#pragma unroll
    for (int mt = 0; mt < 4; ++mt)
#pragma unroll
      for (int nt = 0; nt < 4; ++nt)
        acc[mt][nt] = mfma16(af[mt], bfr[nt], acc[mt][nt]);
    __syncthreads();
  }

  if (z < 2) {
    unsigned short* dst = (z == 0) ? Qb : Kb;
    float sc = (z == 0) ? QSCALE : 1.0f;
#pragma unroll
    for (int nt = 0; nt < 4; ++nt) {
      int n = n0 + wn * 64 + nt * 16 + mrow;
      float bv_ = bias[n];
#pragma unroll
      for (int mt = 0; mt < 4; ++mt) {
        int m = m0 + wm * 64 + mt * 16 + quad * 4;
#pragma unroll
        for (int r = 0; r < 4; ++r) {
          float v = fmaxf(acc[mt][nt][r] + bv_, 0.f) * sc;
          dst[(m + r) * 512 + n] = f2bf(v);
        }
      }
    }
  } else {
    // V: permuted-transposed store (pos = quad*8 + (mt&1)*4 + r in 32-t group)
#pragma unroll
    for (int nt = 0; nt < 4; ++nt) {
      int n = n0 + wn * 64 + nt * 16 + mrow;
      int hh = n >> 6, jj = n & 63;
      float bv_ = bias[n];
#pragma unroll
      for (int mt = 0; mt < 4; ++mt) {
        int grow = m0 + wm * 64 + mt * 16 + quad * 4;
        int bb = grow >> 11, tl = grow & 2047;
        int pos = (tl & ~31) + quad * 8 + (mt & 1) * 4;
        float p0 = fmaxf(acc[mt][nt][0] + bv_, 0.f);
        float p1 = fmaxf(acc[mt][nt][1] + bv_, 0.f);
        float p2 = fmaxf(acc[mt][nt][2] + bv_, 0.f);
        float p3 = fmaxf(acc[mt][nt][3] + bv_, 0.f);
        *(uint2*)(Vt + ((hh * 4 + bb) * 64 + jj) * 2048 + pos) =
            make_uint2(pk2(p0, p1), pk2(p2, p3));
      }
    }
  }
}

// ---------------------------------------------------------------------------
// Kernel 3: attention, key-split q-owner. Grid (hb=32, qt=16, z=2); 256 thr;
// wave w owns q rows q0+w*32..+31 over keys z*1024..+1023 (8 chunks of 128).
// K LDS-staged dbuf (2 x 16 KB, XOR swizzle); V fragments DIRECT from L2
// (swizzle algebra cancels: Vt[(hb*64+dt*16+mrow)*2048 + k + (g*4+quad)*8]).
// Register-dbuf of per-g K/V frags + kbias. QK seeded with kbias; l via
// MFMA vs ones. Epilogue: store UNNORMALIZED partial O (fp32) + per-(h,q)
// partial l; combine/normalize/residual happen fused in ln_kernel.
// ---------------------------------------------------------------------------
__global__ __launch_bounds__(256, 4) void attn_kernel(
    const unsigned short* __restrict__ Qb, const unsigned short* __restrict__ Kb,
    const unsigned short* __restrict__ Vt, const float* __restrict__ kbias,
    float* __restrict__ O0, float* __restrict__ O1,
    float* __restrict__ l0, float* __restrict__ l1) {
  __shared__ char smem[32768];
  unsigned short* KsmS = (unsigned short*)smem;  // [2][8192] shorts

  int hb = blockIdx.x;
  int qt = blockIdx.y;
  int z = blockIdx.z;
  int h = hb >> 2, b = hb & 3;
  int q0 = qt * 128;
  int k0 = z * 1024;
  int tid = threadIdx.x;
  int w = tid >> 6, lane = tid & 63;
  int mrow = lane & 15, quad = lane >> 4;
  int mlow = mrow & 7;

  // K staging source (XOR-swizzled slot->chunk): rows tid>>3 in 0..31
  const unsigned short* gK =
      Kb + (b * 2048 + k0 + (tid >> 3)) * 512 + h * 64 +
      (((tid & 7) ^ ((tid >> 3) & 7)) * 8);
  // V direct-from-L2 base (row = dh block, permuted col order matches P)
  const unsigned short* gVb = Vt + (hb * 64 + mrow) * 2048 + k0;

  // Q B-frags for this wave's 32 q rows: [qn][k-half]
  bf16x8 qf[2][2];
  {
    const unsigned short* qp =
        Qb + (b * 2048 + q0 + w * 32 + mrow) * 512 + h * 64 + quad * 8;
    qf[0][0] = ld_bf8(qp);
    qf[0][1] = ld_bf8(qp + 32);
    qf[1][0] = ld_bf8(qp + 8192);
    qf[1][1] = ld_bf8(qp + 8192 + 32);
  }

  bf16x8 onev;
#pragma unroll
  for (int i = 0; i < 8; ++i) onev[i] = (__bf16)1.0f;

  f32x4 zero = {0.f, 0.f, 0.f, 0.f};
  f32x4 oacc[4][2];  // [dt][qn]: col=dh dt*16+mrow, row=q quad*4+r
#pragma unroll
  for (int i = 0; i < 4; ++i)
#pragma unroll
    for (int j = 0; j < 2; ++j) oacc[i][j] = zero;
  f32x4 lacc[2] = {zero, zero};  // l[q], replicated over cols

  const float* kmC = kbias + b * 2048 + k0 + quad * 4;

  // preload chunk 0 into buf 0
#pragma unroll
  for (int j = 0; j < 4; ++j)
    g2l16(gK + j * 32 * 512, &KsmS[j * 2048 + tid * 8]);

  for (int it = 0; it < 8; ++it) {
    int bi = it & 1;
    int kb = it * 128;  // key offset within this z-half
    __syncthreads();    // drains staging DMA; buf bi ready

    if (it < 7) {
      int nb = 1 - bi;
#pragma unroll
      for (int j = 0; j < 4; ++j)
        g2l16(gK + (kb + 128 + j * 32) * 512, &KsmS[nb * 8192 + j * 2048 + tid * 8]);
    }

    const unsigned short* Kc = KsmS + bi * 8192;

    // register-double-buffered per-g fragments (fully unrolled -> renamed)
    bf16x8 kf[2][4], vf[2][4];
    f32x4 km[2][2];
    auto ldg = [&](int gi, int sl) {
      km[sl][0] = *(const f32x4*)(kmC + kb + gi * 32);
      km[sl][1] = *(const f32x4*)(kmC + kb + gi * 32 + 16);
      kf[sl][0] = ld_bf8(&Kc[(gi * 32 + mrow) * 64 + (quad ^ mlow) * 8]);
      kf[sl][1] = ld_bf8(&Kc[(gi * 32 + mrow) * 64 + ((4 + quad) ^ mlow) * 8]);
      kf[sl][2] = ld_bf8(&Kc[(gi * 32 + 16 + mrow) * 64 + (quad ^ mlow) * 8]);
      kf[sl][3] = ld_bf8(&Kc[(gi * 32 + 16 + mrow) * 64 + ((4 + quad) ^ mlow) * 8]);
#pragma unroll
      for (int dt = 0; dt < 4; ++dt)
        vf[sl][dt] = ld_bf8(gVb + dt * 32768 + kb + (gi * 4 + quad) * 8);
    };

    ldg(0, 0);
#pragma unroll
    for (int g = 0; g < 4; ++g) {
      int cb = g & 1;
      if (g < 3) ldg(g + 1, cb ^ 1);
      __builtin_amdgcn_s_setprio(1);
#pragma unroll
      for (int qn = 0; qn < 2; ++qn) {
        f32x4 s0 = mfma16(kf[cb][0], qf[qn][0], km[cb][0]);
        s0 = mfma16(kf[cb][1], qf[qn][1], s0);
        f32x4 s1 = mfma16(kf[cb][2], qf[qn][0], km[cb][1]);
        s1 = mfma16(kf[cb][3], qf[qn][1], s1);
        f32x4 p0, p1;
#pragma unroll
        for (int r = 0; r < 4; ++r) {
          p0[r] = EXP2F(s0[r]);
          p1[r] = EXP2F(s1[r]);
        }
        bf16x8 pf = __builtin_bit_cast(
            bf16x8, make_uint4(pk2(p0[0], p0[1]), pk2(p0[2], p0[3]),
                               pk2(p1[0], p1[1]), pk2(p1[2], p1[3])));
        lacc[qn] = mfma16(pf, onev, lacc[qn]);
#pragma unroll
        for (int dt = 0; dt < 4; ++dt)
          oacc[dt][qn] = mfma16(pf, vf[cb][dt], oacc[dt][qn]);
      }
      __builtin_amdgcn_s_setprio(0);
    }
  }

  // --- epilogue: store unnormalized partials (no shuffles, no LDS)
  float* Op = z ? O1 : O0;
  float* lp = (z ? l1 : l0) + h * 8192;
#pragma unroll
  for (int qn = 0; qn < 2; ++qn) {
#pragma unroll
    for (int r = 0; r < 4; ++r) {
      int qg = b * 2048 + q0 + w * 32 + qn * 16 + quad * 4 + r;
      if (mrow == 0) lp[qg] = lacc[qn][r];
      float* od = Op + qg * 512 + h * 64 + mrow;
#pragma unroll
      for (int dt = 0; dt < 4; ++dt)
        od[dt * 16] = oacc[dt][qn][r];
    }
  }
}

// ---------------------------------------------------------------------------
// Kernel 4: fused combine + LayerNorm. out (=O0) += O1, scaled per 64-dh
// segment by qmask/(l0_h+l1_h), + queries residual; then LN (unbiased std,
// eps added to std). In-place on d_out.
// ---------------------------------------------------------------------------
__global__ __launch_bounds__(256) void ln_kernel(
    float* __restrict__ out, const float* __restrict__ O1,
    const float* __restrict__ l0, const float* __restrict__ l1,
    const float* __restrict__ qmask, const float* __restrict__ queries,
    const float* __restrict__ gamma, const float* __restrict__ beta) {
  int row = blockIdx.x * 4 + (threadIdx.x >> 6);
  int lane = threadIdx.x & 63;
  int h1 = lane >> 4;      // head of floats 4*lane..4*lane+3 (seg 0..255)
  int h2 = 4 + h1;         // head of floats 256+4*lane..
  float qm = qmask[row];
  float sa = qm / (l0[h1 * 8192 + row] + l1[h1 * 8192 + row]);
  float sb = qm / (l0[h2 * 8192 + row] + l1[h2 * 8192 + row]);
  float* p = out + row * 512;
  const float4* p1v = (const float4*)(O1 + row * 512);
  const float4* pq = (const float4*)(queries + row * 512);
  float4 a1 = ((const float4*)p)[lane];
  float4 a2 = ((const float4*)p)[64 + lane];
  float4 o1 = p1v[lane];
  float4 o2 = p1v[64 + lane];
  float4 q1 = pq[lane];
  float4 q2 = pq[64 + lane];
  float4 v1, v2;
  v1.x = (a1.x + o1.x) * sa + q1.x;
  v1.y = (a1.y + o1.y) * sa + q1.y;
  v1.z = (a1.z + o1.z) * sa + q1.z;
  v1.w = (a1.w + o1.w) * sa + q1.w;
  v2.x = (a2.x + o2.x) * sb + q2.x;
  v2.y = (a2.y + o2.y) * sb + q2.y;
  v2.z = (a2.z + o2.z) * sb + q2.z;
  v2.w = (a2.w + o2.w) * sb + q2.w;
  float s = v1.x + v1.y + v1.z + v1.w + v2.x + v2.y + v2.z + v2.w;
  float sq = v1.x * v1.x + v1.y * v1.y + v1.z * v1.z + v1.w * v1.w +
             v2.x * v2.x + v2.y * v2.y + v2.z * v2.z + v2.w * v2.w;
#pragma unroll
  for (int off = 32; off > 0; off >>= 1) {
    s += __shfl_xor(s, off);
    sq += __shfl_xor(sq, off);
  }
  float mean = s * (1.f / 512.f);
  float var = fmaxf((sq - 512.f * mean * mean) * (1.f / 511.f), 0.f);
  float inv = 1.f / (sqrtf(var) + 1e-8f);
  float4 g1 = ((const float4*)gamma)[lane];
  float4 g2 = ((const float4*)gamma)[64 + lane];
  float4 b1 = ((const float4*)beta)[lane];
  float4 b2 = ((const float4*)beta)[64 + lane];
  v1.x = g1.x * (v1.x - mean) * inv + b1.x;
  v1.y = g1.y * (v1.y - mean) * inv + b1.y;
  v1.z = g1.z * (v1.z - mean) * inv + b1.z;
  v1.w = g1.w * (v1.w - mean) * inv + b1.w;
  v2.x = g2.x * (v2.x - mean) * inv + b2.x;
  v2.y = g2.y * (v2.y - mean) * inv + b2.y;
  v2.z = g2.z * (v2.z - mean) * inv + b2.z;
  v2.w = g2.w * (v2.w - mean) * inv + b2.w;
  ((float4*)p)[lane] = v1;
  ((float4*)p)[64 + lane] = v2;
}

// ---------------------------------------------------------------------------
extern "C" void kernel_launch(void* const* d_in, const int* in_sizes, int n_in,
                              void* d_out, int out_size, void* d_ws, size_t ws_size,
                              hipStream_t stream) {
  (void)in_sizes; (void)n_in; (void)out_size; (void)ws_size;
  const float* queries = (const float*)d_in[0];
  const float* keys    = (const float*)d_in[1];
  const float* values  = (const float*)d_in[2];
  const float* Wq = (const float*)d_in[3];
  const float* bq = (const float*)d_in[4];
  const float* Wk = (const float*)d_in[5];
  const float* bk = (const float*)d_in[6];
  const float* Wv = (const float*)d_in[7];
  const float* bv = (const float*)d_in[8];
  const float* gamma = (const float*)d_in[9];
  const float* beta  = (const float*)d_in[10];
  float* out = (float*)d_out;

  char* ws = (char*)d_ws;
  unsigned short* Qb = (unsigned short*)(ws);                     // 8 MiB
  unsigned short* Kb = (unsigned short*)(ws + 8 * 1024 * 1024);   // 8 MiB
  unsigned short* Vt = (unsigned short*)(ws + 16 * 1024 * 1024);  // 8 MiB
  unsigned short* Wt = (unsigned short*)(ws + 24 * 1024 * 1024);  // 1.5 MiB
  unsigned short* Xbv = (unsigned short*)(ws + 26 * 1024 * 1024); // 8 MiB
  // O1 overlays Wt+Xbv (both dead after proj); written only by attn (after
  // proj in stream order).
  float* O1 = (float*)(ws + 24 * 1024 * 1024);                    // 16 MiB
  float* qmask = (float*)(ws + 40 * 1024 * 1024);                 // 32 KiB
  float* kbias = qmask + 8192;                                    // 32 KiB
  float* l0 = kbias + 8192;                                       // 256 KiB
  float* l1 = l0 + 65536;                                         // 256 KiB

  // Xb for queries/keys staged in d_out (16 MiB, dead until attn writes O0)
  unsigned short* Xbq = (unsigned short*)d_out;
  unsigned short* Xbk = Xbq + 4194304;
  float* O0 = (float*)d_out;

  wt_kernel<<<384, 256, 0, stream>>>(Wq, Wk, Wv, Wt);
  xcvt_kernel<<<6144, 256, 0, stream>>>(queries, keys, values, Xbq, Xbk, Xbv,
                                        qmask, kbias);
  proj_kernel<<<dim3(192, 4), 256, 0, stream>>>(Xbq, Xbk, Xbv, bq, bk, bv,
                                                Wt, Qb, Kb, Vt);
  attn_kernel<<<dim3(32, 16, 2), 256, 0, stream>>>(Qb, Kb, Vt, kbias,
                                                   O0, O1, l0, l1);
  ln_kernel<<<2048, 256, 0, stream>>>(out, O1, l0, l1, qmask, queries,
                                      gamma, beta);
}

// Round 7
// 224.542 us; speedup vs baseline: 1.7960x; 1.7960x over previous
//
#include <hip/hip_runtime.h>

// R14 = R13 with the register regime fixed: attn __launch_bounds__(256,2)
// (cap 256). R13's (256,4) cap-128 repeated the R8/R9 catastrophe: VGPR=64
// split + 796 MB scratch spill (vs ~34 MB real partials), MfmaUtil 5.8%.
// Confirmed compiler behavior: cap-128 + >~100-reg body => 64-reg split +
// spill; cap-256 compiles the same body to ~108 spill-free (R12). 108 VGPR
// -> 16 waves/CU; 32 KB LDS -> 5 blocks/CU; actual occupancy = 4 blocks/CU
// (16 waves/CU, 4/SIMD) WITHOUT the cap. Everything else identical to R13:
// key-split grid (32,16,2), w_q=32, K-only LDS dbuf, V direct from L2,
// unnormalized partial O/l stores, combine fused into ln.

typedef __attribute__((ext_vector_type(8))) __bf16 bf16x8;
typedef __attribute__((ext_vector_type(4))) float f32x4;

#if __has_builtin(__builtin_amdgcn_exp2f)
#define EXP2F __builtin_amdgcn_exp2f
#else
#define EXP2F exp2f
#endif

#define QSCALE (0.125f * 1.4426950408889634f)  // fold /sqrt(64) and ln->log2

__device__ __forceinline__ unsigned short f2bf(float f) {
  return __builtin_bit_cast(unsigned short, (__bf16)f);
}
__device__ __forceinline__ unsigned pk2(float a, float b) {
  return (unsigned)f2bf(a) | ((unsigned)f2bf(b) << 16);
}
__device__ __forceinline__ f32x4 mfma16(bf16x8 a, bf16x8 b, f32x4 c) {
  return __builtin_amdgcn_mfma_f32_16x16x32_bf16(a, b, c, 0, 0, 0);
}
__device__ __forceinline__ bf16x8 ld_bf8(const unsigned short* p) {
  return *(const bf16x8*)p;
}
// async global->LDS, 16 B per lane; LDS dst is wave-uniform base + lane*16
__device__ __forceinline__ void g2l16(const void* g, void* l) {
  __builtin_amdgcn_global_load_lds(
      (const __attribute__((address_space(1))) void*)g,
      (__attribute__((address_space(3))) void*)l, 16, 0, 0);
}

// ---------------------------------------------------------------------------
// Kernel 1: transpose + convert the three 512x512 weight matrices to bf16,
// layout Wt[z][n][k] (n-major) so MFMA B-fragments read contiguous k.
// ---------------------------------------------------------------------------
__global__ __launch_bounds__(256) void wt_kernel(const float* __restrict__ Wq,
                                                 const float* __restrict__ Wk,
                                                 const float* __restrict__ Wv,
                                                 unsigned short* __restrict__ Wt) {
  int idx = blockIdx.x * 256 + threadIdx.x;
  int o = idx * 8;
  int z = o >> 18;
  int rem = o & 262143;
  int n = rem >> 9;
  int k0 = rem & 511;
  const float* W = (z == 0) ? Wq : ((z == 1) ? Wk : Wv);
  unsigned int w[4];
#pragma unroll
  for (int i = 0; i < 4; ++i) {
    unsigned short lo = f2bf(W[(k0 + 2 * i) * 512 + n]);
    unsigned short hi = f2bf(W[(k0 + 2 * i + 1) * 512 + n]);
    w[i] = (unsigned)lo | ((unsigned)hi << 16);
  }
  *(uint4*)(Wt + o) = make_uint4(w[0], w[1], w[2], w[3]);
}

// ---------------------------------------------------------------------------
// Kernel 1b: convert X (queries/keys/values) fp32->bf16 rows, and compute
// the padding masks from exact fp32 row sums: qmask (0/1, multiplicative)
// and kbias (0/-1e30, folded into the QK MFMA accumulator init).
// One wave per 512-float row; 6144 blocks x 4 rows.
// ---------------------------------------------------------------------------
__global__ __launch_bounds__(256) void xcvt_kernel(
    const float* __restrict__ Xq, const float* __restrict__ Xk,
    const float* __restrict__ Xv, unsigned short* __restrict__ Xbq,
    unsigned short* __restrict__ Xbk, unsigned short* __restrict__ Xbv,
    float* __restrict__ qmask, float* __restrict__ kbias) {
  int row = blockIdx.x * 4 + (threadIdx.x >> 6);
  int lane = threadIdx.x & 63;
  int z = row >> 13;
  int r = row & 8191;
  const float* X = (z == 0) ? Xq : ((z == 1) ? Xk : Xv);
  unsigned short* Xb = (z == 0) ? Xbq : ((z == 1) ? Xbk : Xbv);
  const float* p = X + r * 512 + lane * 8;
  f32x4 lo = *(const f32x4*)p;
  f32x4 hi = *(const f32x4*)(p + 4);
  *(uint4*)(Xb + r * 512 + lane * 8) =
      make_uint4(pk2(lo[0], lo[1]), pk2(lo[2], lo[3]), pk2(hi[0], hi[1]),
                 pk2(hi[2], hi[3]));
  if (z < 2) {
    float s = lo[0] + lo[1] + lo[2] + lo[3] + hi[0] + hi[1] + hi[2] + hi[3];
#pragma unroll
    for (int off = 1; off < 64; off <<= 1) s += __shfl_xor(s, off);
    if (lane == 0) {
      if (z == 0)
        qmask[r] = (s == 0.f) ? 0.f : 1.f;
      else
        kbias[r] = (s == 0.f) ? -1.0e30f : 0.f;
    }
  }
}

// ---------------------------------------------------------------------------
// Kernel 2: QKV projection, pure-bf16 double-buffered GEMM, ONE barrier per
// K-step. A and B staged [128][32] shorts with source-side XOR swizzle.
// Grid (192 m-blocks, 4 n-blocks); z = m-block/64. Tile 128x128, BK=32.
// V stored transposed with the permuted intra-32-key order
// (pos = quad*8 + sub*4 + r), matching attn's P register-repack k-order.
// ---------------------------------------------------------------------------
__global__ __launch_bounds__(256, 3) void proj_kernel(
    const unsigned short* __restrict__ Xbq, const unsigned short* __restrict__ Xbk,
    const unsigned short* __restrict__ Xbv, const float* __restrict__ bq,
    const float* __restrict__ bk, const float* __restrict__ bv,
    const unsigned short* __restrict__ Wt, unsigned short* __restrict__ Qb,
    unsigned short* __restrict__ Kb, unsigned short* __restrict__ Vt) {
  __shared__ unsigned short Asm[2][128][32];
  __shared__ unsigned short Bsm[2][128][32];

  int tid = threadIdx.x;
  int m0g = blockIdx.x * 128;
  int z = m0g >> 13;
  int m0 = m0g & 8191;
  int n0 = blockIdx.y * 128;
  const unsigned short* Xb = (z == 0) ? Xbq : ((z == 1) ? Xbk : Xbv);
  const float* bias = (z == 0) ? bq : ((z == 1) ? bk : bv);
  const unsigned short* Wz = Wt + z * 262144;

  int w = tid >> 6, lane = tid & 63;
  int wm = w >> 1, wn = w & 1;
  int mrow = lane & 15, quad = lane >> 4;

  int srow = tid >> 2, sslot = tid & 3;
  int sxs = sslot ^ ((srow >> 1) & 3);
  const unsigned short* gA = Xb + (m0 + srow) * 512 + sxs * 8;
  const unsigned short* gB = Wz + (n0 + srow) * 512 + sxs * 8;
  char* lA = (char*)&Asm[0][0][0] + tid * 16;
  char* lB = (char*)&Bsm[0][0][0] + tid * 16;

  int rs = (quad ^ ((mrow >> 1) & 3)) * 8;

  f32x4 zero = {0.f, 0.f, 0.f, 0.f};
  f32x4 acc[4][4];
#pragma unroll
  for (int i = 0; i < 4; ++i)
#pragma unroll
    for (int j = 0; j < 4; ++j) acc[i][j] = zero;

  g2l16(gA, lA);
  g2l16(gA + 64 * 512, lA + 4096);
  g2l16(gB, lB);
  g2l16(gB + 64 * 512, lB + 4096);
  __syncthreads();

  for (int kc = 0; kc < 16; ++kc) {
    int cur = kc & 1;
    if (kc < 15) {
      int ko = (kc + 1) * 32;
      int nb = cur ^ 1;
      g2l16(gA + ko, lA + nb * 8192);
      g2l16(gA + ko + 64 * 512, lA + nb * 8192 + 4096);
      g2l16(gB + ko, lB + nb * 8192);
      g2l16(gB + ko + 64 * 512, lB + nb * 8192 + 4096);
    }
    bf16x8 af[4], bfr[4];
#pragma unroll
    for (int mt = 0; mt < 4; ++mt)
      af[mt] = ld_bf8(&Asm[cur][wm * 64 + mt * 16 + mrow][rs]);
#pragma unroll
    for (int nt = 0; nt < 4; ++nt)
      bfr[nt] = ld_bf8(&Bsm[cur][wn * 64 + nt * 16 + mrow][rs]);
#pragma unroll
    for (int mt = 0; mt < 4; ++mt)
#pragma unroll
      for (int nt = 0; nt < 4; ++nt)
        acc[mt][nt] = mfma16(af[mt], bfr[nt], acc[mt][nt]);
    __syncthreads();
  }

  if (z < 2) {
    unsigned short* dst = (z == 0) ? Qb : Kb;
    float sc = (z == 0) ? QSCALE : 1.0f;
#pragma unroll
    for (int nt = 0; nt < 4; ++nt) {
      int n = n0 + wn * 64 + nt * 16 + mrow;
      float bv_ = bias[n];
#pragma unroll
      for (int mt = 0; mt < 4; ++mt) {
        int m = m0 + wm * 64 + mt * 16 + quad * 4;
#pragma unroll
        for (int r = 0; r < 4; ++r) {
          float v = fmaxf(acc[mt][nt][r] + bv_, 0.f) * sc;
          dst[(m + r) * 512 + n] = f2bf(v);
        }
      }
    }
  } else {
    // V: permuted-transposed store (pos = quad*8 + (mt&1)*4 + r in 32-t group)
#pragma unroll
    for (int nt = 0; nt < 4; ++nt) {
      int n = n0 + wn * 64 + nt * 16 + mrow;
      int hh = n >> 6, jj = n & 63;
      float bv_ = bias[n];
#pragma unroll
      for (int mt = 0; mt < 4; ++mt) {
        int grow = m0 + wm * 64 + mt * 16 + quad * 4;
        int bb = grow >> 11, tl = grow & 2047;
        int pos = (tl & ~31) + quad * 8 + (mt & 1) * 4;
        float p0 = fmaxf(acc[mt][nt][0] + bv_, 0.f);
        float p1 = fmaxf(acc[mt][nt][1] + bv_, 0.f);
        float p2 = fmaxf(acc[mt][nt][2] + bv_, 0.f);
        float p3 = fmaxf(acc[mt][nt][3] + bv_, 0.f);
        *(uint2*)(Vt + ((hh * 4 + bb) * 64 + jj) * 2048 + pos) =
            make_uint2(pk2(p0, p1), pk2(p2, p3));
      }
    }
  }
}

// ---------------------------------------------------------------------------
// Kernel 3: attention, key-split q-owner. Grid (hb=32, qt=16, z=2); 256 thr;
// wave w owns q rows q0+w*32..+31 over keys z*1024..+1023 (8 chunks of 128).
// K LDS-staged dbuf (2 x 16 KB, XOR swizzle); V fragments DIRECT from L2
// (swizzle algebra cancels: Vt[(hb*64+dt*16+mrow)*2048 + k + (g*4+quad)*8]).
// Register-dbuf of per-g K/V frags + kbias. QK seeded with kbias; l via
// MFMA vs ones. Epilogue: store UNNORMALIZED partial O (fp32) + per-(h,q)
// partial l; combine/normalize/residual happen fused in ln_kernel.
// launch_bounds(256,2): cap-256 -> ~108 VGPR spill-free (cap-128 provably
// forces a 64-reg split + scratch spill on this body: R8/R9/R13).
// ---------------------------------------------------------------------------
__global__ __launch_bounds__(256, 2) void attn_kernel(
    const unsigned short* __restrict__ Qb, const unsigned short* __restrict__ Kb,
    const unsigned short* __restrict__ Vt, const float* __restrict__ kbias,
    float* __restrict__ O0, float* __restrict__ O1,
    float* __restrict__ l0, float* __restrict__ l1) {
  __shared__ char smem[32768];
  unsigned short* KsmS = (unsigned short*)smem;  // [2][8192] shorts

  int hb = blockIdx.x;
  int qt = blockIdx.y;
  int z = blockIdx.z;
  int h = hb >> 2, b = hb & 3;
  int q0 = qt * 128;
  int k0 = z * 1024;
  int tid = threadIdx.x;
  int w = tid >> 6, lane = tid & 63;
  int mrow = lane & 15, quad = lane >> 4;
  int mlow = mrow & 7;

  // K staging source (XOR-swizzled slot->chunk): rows tid>>3 in 0..31
  const unsigned short* gK =
      Kb + (b * 2048 + k0 + (tid >> 3)) * 512 + h * 64 +
      (((tid & 7) ^ ((tid >> 3) & 7)) * 8);
  // V direct-from-L2 base (row = dh block, permuted col order matches P)
  const unsigned short* gVb = Vt + (hb * 64 + mrow) * 2048 + k0;

  // Q B-frags for this wave's 32 q rows: [qn][k-half]
  bf16x8 qf[2][2];
  {
    const unsigned short* qp =
        Qb + (b * 2048 + q0 + w * 32 + mrow) * 512 + h * 64 + quad * 8;
    qf[0][0] = ld_bf8(qp);
    qf[0][1] = ld_bf8(qp + 32);
    qf[1][0] = ld_bf8(qp + 8192);
    qf[1][1] = ld_bf8(qp + 8192 + 32);
  }

  bf16x8 onev;
#pragma unroll
  for (int i = 0; i < 8; ++i) onev[i] = (__bf16)1.0f;

  f32x4 zero = {0.f, 0.f, 0.f, 0.f};
  f32x4 oacc[4][2];  // [dt][qn]: col=dh dt*16+mrow, row=q quad*4+r
#pragma unroll
  for (int i = 0; i < 4; ++i)
#pragma unroll
    for (int j = 0; j < 2; ++j) oacc[i][j] = zero;
  f32x4 lacc[2] = {zero, zero};  // l[q], replicated over cols

  const float* kmC = kbias + b * 2048 + k0 + quad * 4;

  // preload chunk 0 into buf 0
#pragma unroll
  for (int j = 0; j < 4; ++j)
    g2l16(gK + j * 32 * 512, &KsmS[j * 2048 + tid * 8]);

  for (int it = 0; it < 8; ++it) {
    int bi = it & 1;
    int kb = it * 128;  // key offset within this z-half
    __syncthreads();    // drains staging DMA; buf bi ready

    if (it < 7) {
      int nb = 1 - bi;
#pragma unroll
      for (int j = 0; j < 4; ++j)
        g2l16(gK + (kb + 128 + j * 32) * 512, &KsmS[nb * 8192 + j * 2048 + tid * 8]);
    }

    const unsigned short* Kc = KsmS + bi * 8192;

    // register-double-buffered per-g fragments (fully unrolled -> renamed)
    bf16x8 kf[2][4], vf[2][4];
    f32x4 km[2][2];
    auto ldg = [&](int gi, int sl) {
      km[sl][0] = *(const f32x4*)(kmC + kb + gi * 32);
      km[sl][1] = *(const f32x4*)(kmC + kb + gi * 32 + 16);
      kf[sl][0] = ld_bf8(&Kc[(gi * 32 + mrow) * 64 + (quad ^ mlow) * 8]);
      kf[sl][1] = ld_bf8(&Kc[(gi * 32 + mrow) * 64 + ((4 + quad) ^ mlow) * 8]);
      kf[sl][2] = ld_bf8(&Kc[(gi * 32 + 16 + mrow) * 64 + (quad ^ mlow) * 8]);
      kf[sl][3] = ld_bf8(&Kc[(gi * 32 + 16 + mrow) * 64 + ((4 + quad) ^ mlow) * 8]);
#pragma unroll
      for (int dt = 0; dt < 4; ++dt)
        vf[sl][dt] = ld_bf8(gVb + dt * 32768 + kb + (gi * 4 + quad) * 8);
    };

    ldg(0, 0);
#pragma unroll
    for (int g = 0; g < 4; ++g) {
      int cb = g & 1;
      if (g < 3) ldg(g + 1, cb ^ 1);
      __builtin_amdgcn_s_setprio(1);
#pragma unroll
      for (int qn = 0; qn < 2; ++qn) {
        f32x4 s0 = mfma16(kf[cb][0], qf[qn][0], km[cb][0]);
        s0 = mfma16(kf[cb][1], qf[qn][1], s0);
        f32x4 s1 = mfma16(kf[cb][2], qf[qn][0], km[cb][1]);
        s1 = mfma16(kf[cb][3], qf[qn][1], s1);
        f32x4 p0, p1;
#pragma unroll
        for (int r = 0; r < 4; ++r) {
          p0[r] = EXP2F(s0[r]);
          p1[r] = EXP2F(s1[r]);
        }
        bf16x8 pf = __builtin_bit_cast(
            bf16x8, make_uint4(pk2(p0[0], p0[1]), pk2(p0[2], p0[3]),
                               pk2(p1[0], p1[1]), pk2(p1[2], p1[3])));
        lacc[qn] = mfma16(pf, onev, lacc[qn]);
#pragma unroll
        for (int dt = 0; dt < 4; ++dt)
          oacc[dt][qn] = mfma16(pf, vf[cb][dt], oacc[dt][qn]);
      }
      __builtin_amdgcn_s_setprio(0);
    }
  }

  // --- epilogue: store unnormalized partials (no shuffles, no LDS)
  float* Op = z ? O1 : O0;
  float* lp = (z ? l1 : l0) + h * 8192;
#pragma unroll
  for (int qn = 0; qn < 2; ++qn) {
#pragma unroll
    for (int r = 0; r < 4; ++r) {
      int qg = b * 2048 + q0 + w * 32 + qn * 16 + quad * 4 + r;
      if (mrow == 0) lp[qg] = lacc[qn][r];
      float* od = Op + qg * 512 + h * 64 + mrow;
#pragma unroll
      for (int dt = 0; dt < 4; ++dt)
        od[dt * 16] = oacc[dt][qn][r];
    }
  }
}

// ---------------------------------------------------------------------------
// Kernel 4: fused combine + LayerNorm. out (=O0) += O1, scaled per 64-dh
// segment by qmask/(l0_h+l1_h), + queries residual; then LN (unbiased std,
// eps added to std). In-place on d_out.
// ---------------------------------------------------------------------------
__global__ __launch_bounds__(256) void ln_kernel(
    float* __restrict__ out, const float* __restrict__ O1,
    const float* __restrict__ l0, const float* __restrict__ l1,
    const float* __restrict__ qmask, const float* __restrict__ queries,
    const float* __restrict__ gamma, const float* __restrict__ beta) {
  int row = blockIdx.x * 4 + (threadIdx.x >> 6);
  int lane = threadIdx.x & 63;
  int h1 = lane >> 4;      // head of floats 4*lane..4*lane+3 (seg 0..255)
  int h2 = 4 + h1;         // head of floats 256+4*lane..
  float qm = qmask[row];
  float sa = qm / (l0[h1 * 8192 + row] + l1[h1 * 8192 + row]);
  float sb = qm / (l0[h2 * 8192 + row] + l1[h2 * 8192 + row]);
  float* p = out + row * 512;
  const float4* p1v = (const float4*)(O1 + row * 512);
  const float4* pq = (const float4*)(queries + row * 512);
  float4 a1 = ((const float4*)p)[lane];
  float4 a2 = ((const float4*)p)[64 + lane];
  float4 o1 = p1v[lane];
  float4 o2 = p1v[64 + lane];
  float4 q1 = pq[lane];
  float4 q2 = pq[64 + lane];
  float4 v1, v2;
  v1.x = (a1.x + o1.x) * sa + q1.x;
  v1.y = (a1.y + o1.y) * sa + q1.y;
  v1.z = (a1.z + o1.z) * sa + q1.z;
  v1.w = (a1.w + o1.w) * sa + q1.w;
  v2.x = (a2.x + o2.x) * sb + q2.x;
  v2.y = (a2.y + o2.y) * sb + q2.y;
  v2.z = (a2.z + o2.z) * sb + q2.z;
  v2.w = (a2.w + o2.w) * sb + q2.w;
  float s = v1.x + v1.y + v1.z + v1.w + v2.x + v2.y + v2.z + v2.w;
  float sq = v1.x * v1.x + v1.y * v1.y + v1.z * v1.z + v1.w * v1.w +
             v2.x * v2.x + v2.y * v2.y + v2.z * v2.z + v2.w * v2.w;
#pragma unroll
  for (int off = 32; off > 0; off >>= 1) {
    s += __shfl_xor(s, off);
    sq += __shfl_xor(sq, off);
  }
  float mean = s * (1.f / 512.f);
  float var = fmaxf((sq - 512.f * mean * mean) * (1.f / 511.f), 0.f);
  float inv = 1.f / (sqrtf(var) + 1e-8f);
  float4 g1 = ((const float4*)gamma)[lane];
  float4 g2 = ((const float4*)gamma)[64 + lane];
  float4 b1 = ((const float4*)beta)[lane];
  float4 b2 = ((const float4*)beta)[64 + lane];
  v1.x = g1.x * (v1.x - mean) * inv + b1.x;
  v1.y = g1.y * (v1.y - mean) * inv + b1.y;
  v1.z = g1.z * (v1.z - mean) * inv + b1.z;
  v1.w = g1.w * (v1.w - mean) * inv + b1.w;
  v2.x = g2.x * (v2.x - mean) * inv + b2.x;
  v2.y = g2.y * (v2.y - mean) * inv + b2.y;
  v2.z = g2.z * (v2.z - mean) * inv + b2.z;
  v2.w = g2.w * (v2.w - mean) * inv + b2.w;
  ((float4*)p)[lane] = v1;
  ((float4*)p)[64 + lane] = v2;
}

// ---------------------------------------------------------------------------
extern "C" void kernel_launch(void* const* d_in, const int* in_sizes, int n_in,
                              void* d_out, int out_size, void* d_ws, size_t ws_size,
                              hipStream_t stream) {
  (void)in_sizes; (void)n_in; (void)out_size; (void)ws_size;
  const float* queries = (const float*)d_in[0];
  const float* keys    = (const float*)d_in[1];
  const float* values  = (const float*)d_in[2];
  const float* Wq = (const float*)d_in[3];
  const float* bq = (const float*)d_in[4];
  const float* Wk = (const float*)d_in[5];
  const float* bk = (const float*)d_in[6];
  const float* Wv = (const float*)d_in[7];
  const float* bv = (const float*)d_in[8];
  const float* gamma = (const float*)d_in[9];
  const float* beta  = (const float*)d_in[10];
  float* out = (float*)d_out;

  char* ws = (char*)d_ws;
  unsigned short* Qb = (unsigned short*)(ws);                     // 8 MiB
  unsigned short* Kb = (unsigned short*)(ws + 8 * 1024 * 1024);   // 8 MiB
  unsigned short* Vt = (unsigned short*)(ws + 16 * 1024 * 1024);  // 8 MiB
  unsigned short* Wt = (unsigned short*)(ws + 24 * 1024 * 1024);  // 1.5 MiB
  unsigned short* Xbv = (unsigned short*)(ws + 26 * 1024 * 1024); // 8 MiB
  // O1 overlays Wt+Xbv (both dead after proj); written only by attn (after
  // proj in stream order).
  float* O1 = (float*)(ws + 24 * 1024 * 1024);                    // 16 MiB
  float* qmask = (float*)(ws + 40 * 1024 * 1024);                 // 32 KiB
  float* kbias = qmask + 8192;                                    // 32 KiB
  float* l0 = kbias + 8192;                                       // 256 KiB
  float* l1 = l0 + 65536;                                         // 256 KiB

  // Xb for queries/keys staged in d_out (16 MiB, dead until attn writes O0)
  unsigned short* Xbq = (unsigned short*)d_out;
  unsigned short* Xbk = Xbq + 4194304;
  float* O0 = (float*)d_out;

  wt_kernel<<<384, 256, 0, stream>>>(Wq, Wk, Wv, Wt);
  xcvt_kernel<<<6144, 256, 0, stream>>>(queries, keys, values, Xbq, Xbk, Xbv,
                                        qmask, kbias);
  proj_kernel<<<dim3(192, 4), 256, 0, stream>>>(Xbq, Xbk, Xbv, bq, bk, bv,
                                                Wt, Qb, Kb, Vt);
  attn_kernel<<<dim3(32, 16, 2), 256, 0, stream>>>(Qb, Kb, Vt, kbias,
                                                   O0, O1, l0, l1);
  ln_kernel<<<2048, 256, 0, stream>>>(out, O1, l0, l1, qmask, queries,
                                      gamma, beta);
}

// Round 8
// 186.310 us; speedup vs baseline: 2.1646x; 1.2052x over previous
//
#include <hip/hip_runtime.h>

// R15: (1) attn: key-split (z=2) KEPT, V restored to LDS (R14's V-direct
// read 64 cache lines per vf load at 4KB stride -- the 33us regression).
// Chunk 64 keys: K(2x8KB)+V(2x8KB)=32KB LDS, VGPR ~92-120 under proven
// (256,2) regime -> 4-5 blocks/CU resident = 16 waves/CU = 4/SIMD at
// w_q=32: the occupancy x intensity combination R10/R12/R14 each half-had.
// Same staging/read swizzle algebra with 8-slot rows (quarter-wave: 2
// lanes/slot = free). Partial-O/l epilogue + fused combine-ln verbatim
// (verified twice). (2) wt rebuilt as LDS-transpose tiles (old version
// read W columns at 4B/64B-line = 16x over-fetch) and merged with xcvt
// into one prep kernel (one fewer launch gap).

typedef __attribute__((ext_vector_type(8))) __bf16 bf16x8;
typedef __attribute__((ext_vector_type(4))) float f32x4;

#if __has_builtin(__builtin_amdgcn_exp2f)
#define EXP2F __builtin_amdgcn_exp2f
#else
#define EXP2F exp2f
#endif

#define QSCALE (0.125f * 1.4426950408889634f)  // fold /sqrt(64) and ln->log2

__device__ __forceinline__ unsigned short f2bf(float f) {
  return __builtin_bit_cast(unsigned short, (__bf16)f);
}
__device__ __forceinline__ unsigned pk2(float a, float b) {
  return (unsigned)f2bf(a) | ((unsigned)f2bf(b) << 16);
}
__device__ __forceinline__ f32x4 mfma16(bf16x8 a, bf16x8 b, f32x4 c) {
  return __builtin_amdgcn_mfma_f32_16x16x32_bf16(a, b, c, 0, 0, 0);
}
__device__ __forceinline__ bf16x8 ld_bf8(const unsigned short* p) {
  return *(const bf16x8*)p;
}
// async global->LDS, 16 B per lane; LDS dst is wave-uniform base + lane*16
__device__ __forceinline__ void g2l16(const void* g, void* l) {
  __builtin_amdgcn_global_load_lds(
      (const __attribute__((address_space(1))) void*)g,
      (__attribute__((address_space(3))) void*)l, 16, 0, 0);
}

// ---------------------------------------------------------------------------
// Kernel 1: prep = xcvt (blocks 0..6143) + wt LDS-transpose (blocks 6144+).
// xcvt: X fp32->bf16 + qmask (0/1) / kbias (0/-1e30) from exact fp32 sums.
// wt: 64x64 tiles of W read coalesced, transposed via padded LDS, written
// as bf16 Wt[z][n][k] coalesced in k.
// ---------------------------------------------------------------------------
__global__ __launch_bounds__(256) void prep_kernel(
    const float* __restrict__ Xq, const float* __restrict__ Xk,
    const float* __restrict__ Xv, const float* __restrict__ Wq,
    const float* __restrict__ Wk, const float* __restrict__ Wv,
    unsigned short* __restrict__ Xbq, unsigned short* __restrict__ Xbk,
    unsigned short* __restrict__ Xbv, unsigned short* __restrict__ Wt,
    float* __restrict__ qmask, float* __restrict__ kbias) {
  __shared__ float T[64][65];
  int tid = threadIdx.x;
  if (blockIdx.x < 6144) {
    int row = blockIdx.x * 4 + (tid >> 6);
    int lane = tid & 63;
    int z = row >> 13;
    int r = row & 8191;
    const float* X = (z == 0) ? Xq : ((z == 1) ? Xk : Xv);
    unsigned short* Xb = (z == 0) ? Xbq : ((z == 1) ? Xbk : Xbv);
    const float* p = X + r * 512 + lane * 8;
    f32x4 lo = *(const f32x4*)p;
    f32x4 hi = *(const f32x4*)(p + 4);
    *(uint4*)(Xb + r * 512 + lane * 8) =
        make_uint4(pk2(lo[0], lo[1]), pk2(lo[2], lo[3]), pk2(hi[0], hi[1]),
                   pk2(hi[2], hi[3]));
    if (z < 2) {
      float s = lo[0] + lo[1] + lo[2] + lo[3] + hi[0] + hi[1] + hi[2] + hi[3];
#pragma unroll
      for (int off = 1; off < 64; off <<= 1) s += __shfl_xor(s, off);
      if (lane == 0) {
        if (z == 0)
          qmask[r] = (s == 0.f) ? 0.f : 1.f;
        else
          kbias[r] = (s == 0.f) ? -1.0e30f : 0.f;
      }
    }
  } else {
    int bid = blockIdx.x - 6144;  // 0..191
    int z = bid >> 6;
    int t = bid & 63;
    int r0 = (t >> 3) * 64;  // k-tile base (W row)
    int c0 = (t & 7) * 64;   // n-tile base (W col)
    const float* W = (z == 0) ? Wq : ((z == 1) ? Wk : Wv);
    int tr = tid >> 4, tc = tid & 15;
#pragma unroll
    for (int j = 0; j < 4; ++j) {
      int row = r0 + tr + j * 16;
      float4 v = *(const float4*)&W[row * 512 + c0 + tc * 4];
      T[tc * 4 + 0][tr + j * 16] = v.x;
      T[tc * 4 + 1][tr + j * 16] = v.y;
      T[tc * 4 + 2][tr + j * 16] = v.z;
      T[tc * 4 + 3][tr + j * 16] = v.w;
    }
    __syncthreads();
    unsigned short* Wz = Wt + z * 262144;
#pragma unroll
    for (int j = 0; j < 4; ++j) {
      int nl = tr + j * 16;  // local n (W col)
      int kl = tc * 4;       // local k
      float a0 = T[nl][kl], a1 = T[nl][kl + 1];
      float a2 = T[nl][kl + 2], a3 = T[nl][kl + 3];
      *(uint2*)(Wz + (c0 + nl) * 512 + r0 + kl) =
          make_uint2(pk2(a0, a1), pk2(a2, a3));
    }
  }
}

// ---------------------------------------------------------------------------
// Kernel 2: QKV projection, pure-bf16 double-buffered GEMM, ONE barrier per
// K-step. A and B staged [128][32] shorts with source-side XOR swizzle.
// Grid (192 m-blocks, 4 n-blocks); z = m-block/64. Tile 128x128, BK=32.
// V stored transposed with the permuted intra-32-key order
// (pos = quad*8 + sub*4 + r), matching attn's P register-repack k-order.
// ---------------------------------------------------------------------------
__global__ __launch_bounds__(256, 3) void proj_kernel(
    const unsigned short* __restrict__ Xbq, const unsigned short* __restrict__ Xbk,
    const unsigned short* __restrict__ Xbv, const float* __restrict__ bq,
    const float* __restrict__ bk, const float* __restrict__ bv,
    const unsigned short* __restrict__ Wt, unsigned short* __restrict__ Qb,
    unsigned short* __restrict__ Kb, unsigned short* __restrict__ Vt) {
  __shared__ unsigned short Asm[2][128][32];
  __shared__ unsigned short Bsm[2][128][32];

  int tid = threadIdx.x;
  int m0g = blockIdx.x * 128;
  int z = m0g >> 13;
  int m0 = m0g & 8191;
  int n0 = blockIdx.y * 128;
  const unsigned short* Xb = (z == 0) ? Xbq : ((z == 1) ? Xbk : Xbv);
  const float* bias = (z == 0) ? bq : ((z == 1) ? bk : bv);
  const unsigned short* Wz = Wt + z * 262144;

  int w = tid >> 6, lane = tid & 63;
  int wm = w >> 1, wn = w & 1;
  int mrow = lane & 15, quad = lane >> 4;

  int srow = tid >> 2, sslot = tid & 3;
  int sxs = sslot ^ ((srow >> 1) & 3);
  const unsigned short* gA = Xb + (m0 + srow) * 512 + sxs * 8;
  const unsigned short* gB = Wz + (n0 + srow) * 512 + sxs * 8;
  char* lA = (char*)&Asm[0][0][0] + tid * 16;
  char* lB = (char*)&Bsm[0][0][0] + tid * 16;

  int rs = (quad ^ ((mrow >> 1) & 3)) * 8;

  f32x4 zero = {0.f, 0.f, 0.f, 0.f};
  f32x4 acc[4][4];
#pragma unroll
  for (int i = 0; i < 4; ++i)
#pragma unroll
    for (int j = 0; j < 4; ++j) acc[i][j] = zero;

  g2l16(gA, lA);
  g2l16(gA + 64 * 512, lA + 4096);
  g2l16(gB, lB);
  g2l16(gB + 64 * 512, lB + 4096);
  __syncthreads();

  for (int kc = 0; kc < 16; ++kc) {
    int cur = kc & 1;
    if (kc < 15) {
      int ko = (kc + 1) * 32;
      int nb = cur ^ 1;
      g2l16(gA + ko, lA + nb * 8192);
      g2l16(gA + ko + 64 * 512, lA + nb * 8192 + 4096);
      g2l16(gB + ko, lB + nb * 8192);
      g2l16(gB + ko + 64 * 512, lB + nb * 8192 + 4096);
    }
    bf16x8 af[4], bfr[4];
#pragma unroll
    for (int mt = 0; mt < 4; ++mt)
      af[mt] = ld_bf8(&Asm[cur][wm * 64 + mt * 16 + mrow][rs]);
#pragma unroll
    for (int nt = 0; nt < 4; ++nt)
      bfr[nt] = ld_bf8(&Bsm[cur][wn * 64 + nt * 16 + mrow][rs]);
#pragma unroll
    for (int mt = 0; mt < 4; ++mt)
#pragma unroll
      for (int nt = 0; nt < 4; ++nt)
        acc[mt][nt] = mfma16(af[mt], bfr[nt], acc[mt][nt]);
    __syncthreads();
  }

  if (z < 2) {
    unsigned short* dst = (z == 0) ? Qb : Kb;
    float sc = (z == 0) ? QSCALE : 1.0f;
#pragma unroll
    for (int nt = 0; nt < 4; ++nt) {
      int n = n0 + wn * 64 + nt * 16 + mrow;
      float bv_ = bias[n];
#pragma unroll
      for (int mt = 0; mt < 4; ++mt) {
        int m = m0 + wm * 64 + mt * 16 + quad * 4;
#pragma unroll
        for (int r = 0; r < 4; ++r) {
          float v = fmaxf(acc[mt][nt][r] + bv_, 0.f) * sc;
          dst[(m + r) * 512 + n] = f2bf(v);
        }
      }
    }
  } else {
    // V: permuted-transposed store (pos = quad*8 + (mt&1)*4 + r in 32-t group)
#pragma unroll
    for (int nt = 0; nt < 4; ++nt) {
      int n = n0 + wn * 64 + nt * 16 + mrow;
      int hh = n >> 6, jj = n & 63;
      float bv_ = bias[n];
#pragma unroll
      for (int mt = 0; mt < 4; ++mt) {
        int grow = m0 + wm * 64 + mt * 16 + quad * 4;
        int bb = grow >> 11, tl = grow & 2047;
        int pos = (tl & ~31) + quad * 8 + (mt & 1) * 4;
        float p0 = fmaxf(acc[mt][nt][0] + bv_, 0.f);
        float p1 = fmaxf(acc[mt][nt][1] + bv_, 0.f);
        float p2 = fmaxf(acc[mt][nt][2] + bv_, 0.f);
        float p3 = fmaxf(acc[mt][nt][3] + bv_, 0.f);
        *(uint2*)(Vt + ((hh * 4 + bb) * 64 + jj) * 2048 + pos) =
            make_uint2(pk2(p0, p1), pk2(p2, p3));
      }
    }
  }
}

// ---------------------------------------------------------------------------
// Kernel 3: attention, key-split q-owner, 64-key chunks. Grid (32,16,2);
// 256 thr, wave w owns q rows q0+w*32..+31 over keys z*1024..+1023
// (16 chunks of 64). K+V LDS dbuf 32 KB total (XOR-swizzled staging, 8-slot
// rows; quarter-wave 2 lanes/slot = conflict-free). Register-dbuf of per-g
// frags. QK seeded with kbias; l via MFMA vs ones. Epilogue: unnormalized
// partial O + per-(h,q) l; combine fused in ln. (256,2): cap-256 regime
// (cap-128 provably spills this body: R8/R9/R13). ~4 blocks/CU resident
// -> 16 waves/CU = 4/SIMD at w_q=32.
// ---------------------------------------------------------------------------
__global__ __launch_bounds__(256, 2) void attn_kernel(
    const unsigned short* __restrict__ Qb, const unsigned short* __restrict__ Kb,
    const unsigned short* __restrict__ Vt, const float* __restrict__ kbias,
    float* __restrict__ O0, float* __restrict__ O1,
    float* __restrict__ l0, float* __restrict__ l1) {
  __shared__ char smem[32768];
  unsigned short* KsmS = (unsigned short*)smem;            // [2][4096]
  unsigned short* VsmS = (unsigned short*)(smem + 16384);  // [2][4096]

  int hb = blockIdx.x;
  int qt = blockIdx.y;
  int z = blockIdx.z;
  int h = hb >> 2, b = hb & 3;
  int q0 = qt * 128;
  int k0 = z * 1024;
  int tid = threadIdx.x;
  int w = tid >> 6, lane = tid & 63;
  int mrow = lane & 15, quad = lane >> 4;
  int mlow = mrow & 7;

  // staging sources (XOR-swizzled slot->chunk), rows tid>>3 in 0..31 (+32):
  // K: key-rows x 64 dh shorts (8 slots); V: dh-rows x 64 key shorts (8 slots)
  int ssl = ((tid & 7) ^ ((tid >> 3) & 7)) * 8;
  const unsigned short* gK = Kb + (b * 2048 + k0 + (tid >> 3)) * 512 + h * 64 + ssl;
  const unsigned short* gV = Vt + (hb * 64 + (tid >> 3)) * 2048 + k0 + ssl;

  // Q B-frags for this wave's 32 q rows: [qn][k-half]
  bf16x8 qf[2][2];
  {
    const unsigned short* qp =
        Qb + (b * 2048 + q0 + w * 32 + mrow) * 512 + h * 64 + quad * 8;
    qf[0][0] = ld_bf8(qp);
    qf[0][1] = ld_bf8(qp + 32);
    qf[1][0] = ld_bf8(qp + 8192);
    qf[1][1] = ld_bf8(qp + 8192 + 32);
  }

  bf16x8 onev;
#pragma unroll
  for (int i = 0; i < 8; ++i) onev[i] = (__bf16)1.0f;

  f32x4 zero = {0.f, 0.f, 0.f, 0.f};
  f32x4 oacc[4][2];  // [dt][qn]: col=dh dt*16+mrow, row=q quad*4+r
#pragma unroll
  for (int i = 0; i < 4; ++i)
#pragma unroll
    for (int j = 0; j < 2; ++j) oacc[i][j] = zero;
  f32x4 lacc[2] = {zero, zero};  // l[q], replicated over cols

  const float* kmC = kbias + b * 2048 + k0 + quad * 4;

  // preload chunk 0 into buf 0
#pragma unroll
  for (int j = 0; j < 2; ++j) {
    g2l16(gK + j * 32 * 512, &KsmS[j * 2048 + tid * 8]);
    g2l16(gV + j * 32 * 2048, &VsmS[j * 2048 + tid * 8]);
  }

  for (int it = 0; it < 16; ++it) {
    int bi = it & 1;
    int kb = it * 64;  // key offset within this z-half
    __syncthreads();   // drains staging DMA; buf bi ready

    if (it < 15) {
      int nb = 1 - bi;
#pragma unroll
      for (int j = 0; j < 2; ++j) {
        g2l16(gK + (kb + 64 + j * 32) * 512, &KsmS[nb * 4096 + j * 2048 + tid * 8]);
        g2l16(gV + kb + 64 + j * 32 * 2048, &VsmS[nb * 4096 + j * 2048 + tid * 8]);
      }
    }

    const unsigned short* Kc = KsmS + bi * 4096;
    const unsigned short* Vc = VsmS + bi * 4096;

    // register-double-buffered per-g fragments (g in 0..1)
    bf16x8 kf[2][4], vf[2][4];
    f32x4 km[2][2];
    auto ldg = [&](int gi, int sl) {
      km[sl][0] = *(const f32x4*)(kmC + kb + gi * 32);
      km[sl][1] = *(const f32x4*)(kmC + kb + gi * 32 + 16);
      kf[sl][0] = ld_bf8(&Kc[(gi * 32 + mrow) * 64 + (quad ^ mlow) * 8]);
      kf[sl][1] = ld_bf8(&Kc[(gi * 32 + mrow) * 64 + ((4 + quad) ^ mlow) * 8]);
      kf[sl][2] = ld_bf8(&Kc[(gi * 32 + 16 + mrow) * 64 + (quad ^ mlow) * 8]);
      kf[sl][3] = ld_bf8(&Kc[(gi * 32 + 16 + mrow) * 64 + ((4 + quad) ^ mlow) * 8]);
#pragma unroll
      for (int dt = 0; dt < 4; ++dt)
        vf[sl][dt] =
            ld_bf8(&Vc[(dt * 16 + mrow) * 64 + ((gi * 4 + quad) ^ mlow) * 8]);
    };

    ldg(0, 0);
#pragma unroll
    for (int g = 0; g < 2; ++g) {
      int cb = g & 1;
      if (g < 1) ldg(1, 1);
      __builtin_amdgcn_s_setprio(1);
#pragma unroll
      for (int qn = 0; qn < 2; ++qn) {
        f32x4 s0 = mfma16(kf[cb][0], qf[qn][0], km[cb][0]);
        s0 = mfma16(kf[cb][1], qf[qn][1], s0);
        f32x4 s1 = mfma16(kf[cb][2], qf[qn][0], km[cb][1]);
        s1 = mfma16(kf[cb][3], qf[qn][1], s1);
        f32x4 p0, p1;
#pragma unroll
        for (int r = 0; r < 4; ++r) {
          p0[r] = EXP2F(s0[r]);
          p1[r] = EXP2F(s1[r]);
        }
        bf16x8 pf = __builtin_bit_cast(
            bf16x8, make_uint4(pk2(p0[0], p0[1]), pk2(p0[2], p0[3]),
                               pk2(p1[0], p1[1]), pk2(p1[2], p1[3])));
        lacc[qn] = mfma16(pf, onev, lacc[qn]);
#pragma unroll
        for (int dt = 0; dt < 4; ++dt)
          oacc[dt][qn] = mfma16(pf, vf[cb][dt], oacc[dt][qn]);
      }
      __builtin_amdgcn_s_setprio(0);
    }
  }

  // --- epilogue: store unnormalized partials (no shuffles, no LDS)
  float* Op = z ? O1 : O0;
  float* lp = (z ? l1 : l0) + h * 8192;
#pragma unroll
  for (int qn = 0; qn < 2; ++qn) {
#pragma unroll
    for (int r = 0; r < 4; ++r) {
      int qg = b * 2048 + q0 + w * 32 + qn * 16 + quad * 4 + r;
      if (mrow == 0) lp[qg] = lacc[qn][r];
      float* od = Op + qg * 512 + h * 64 + mrow;
#pragma unroll
      for (int dt = 0; dt < 4; ++dt)
        od[dt * 16] = oacc[dt][qn][r];
    }
  }
}

// ---------------------------------------------------------------------------
// Kernel 4: fused combine + LayerNorm. out (=O0) += O1, scaled per 64-dh
// segment by qmask/(l0_h+l1_h), + queries residual; then LN (unbiased std,
// eps added to std). In-place on d_out.
// ---------------------------------------------------------------------------
__global__ __launch_bounds__(256) void ln_kernel(
    float* __restrict__ out, const float* __restrict__ O1,
    const float* __restrict__ l0, const float* __restrict__ l1,
    const float* __restrict__ qmask, const float* __restrict__ queries,
    const float* __restrict__ gamma, const float* __restrict__ beta) {
  int row = blockIdx.x * 4 + (threadIdx.x >> 6);
  int lane = threadIdx.x & 63;
  int h1 = lane >> 4;      // head of floats 4*lane..4*lane+3 (seg 0..255)
  int h2 = 4 + h1;         // head of floats 256+4*lane..
  float qm = qmask[row];
  float sa = qm / (l0[h1 * 8192 + row] + l1[h1 * 8192 + row]);
  float sb = qm / (l0[h2 * 8192 + row] + l1[h2 * 8192 + row]);
  float* p = out + row * 512;
  const float4* p1v = (const float4*)(O1 + row * 512);
  const float4* pq = (const float4*)(queries + row * 512);
  float4 a1 = ((const float4*)p)[lane];
  float4 a2 = ((const float4*)p)[64 + lane];
  float4 o1 = p1v[lane];
  float4 o2 = p1v[64 + lane];
  float4 q1 = pq[lane];
  float4 q2 = pq[64 + lane];
  float4 v1, v2;
  v1.x = (a1.x + o1.x) * sa + q1.x;
  v1.y = (a1.y + o1.y) * sa + q1.y;
  v1.z = (a1.z + o1.z) * sa + q1.z;
  v1.w = (a1.w + o1.w) * sa + q1.w;
  v2.x = (a2.x + o2.x) * sb + q2.x;
  v2.y = (a2.y + o2.y) * sb + q2.y;
  v2.z = (a2.z + o2.z) * sb + q2.z;
  v2.w = (a2.w + o2.w) * sb + q2.w;
  float s = v1.x + v1.y + v1.z + v1.w + v2.x + v2.y + v2.z + v2.w;
  float sq = v1.x * v1.x + v1.y * v1.y + v1.z * v1.z + v1.w * v1.w +
             v2.x * v2.x + v2.y * v2.y + v2.z * v2.z + v2.w * v2.w;
#pragma unroll
  for (int off = 32; off > 0; off >>= 1) {
    s += __shfl_xor(s, off);
    sq += __shfl_xor(sq, off);
  }
  float mean = s * (1.f / 512.f);
  float var = fmaxf((sq - 512.f * mean * mean) * (1.f / 511.f), 0.f);
  float inv = 1.f / (sqrtf(var) + 1e-8f);
  float4 g1 = ((const float4*)gamma)[lane];
  float4 g2 = ((const float4*)gamma)[64 + lane];
  float4 b1 = ((const float4*)beta)[lane];
  float4 b2 = ((const float4*)beta)[64 + lane];
  v1.x = g1.x * (v1.x - mean) * inv + b1.x;
  v1.y = g1.y * (v1.y - mean) * inv + b1.y;
  v1.z = g1.z * (v1.z - mean) * inv + b1.z;
  v1.w = g1.w * (v1.w - mean) * inv + b1.w;
  v2.x = g2.x * (v2.x - mean) * inv + b2.x;
  v2.y = g2.y * (v2.y - mean) * inv + b2.y;
  v2.z = g2.z * (v2.z - mean) * inv + b2.z;
  v2.w = g2.w * (v2.w - mean) * inv + b2.w;
  ((float4*)p)[lane] = v1;
  ((float4*)p)[64 + lane] = v2;
}

// ---------------------------------------------------------------------------
extern "C" void kernel_launch(void* const* d_in, const int* in_sizes, int n_in,
                              void* d_out, int out_size, void* d_ws, size_t ws_size,
                              hipStream_t stream) {
  (void)in_sizes; (void)n_in; (void)out_size; (void)ws_size;
  const float* queries = (const float*)d_in[0];
  const float* keys    = (const float*)d_in[1];
  const float* values  = (const float*)d_in[2];
  const float* Wq = (const float*)d_in[3];
  const float* bq = (const float*)d_in[4];
  const float* Wk = (const float*)d_in[5];
  const float* bk = (const float*)d_in[6];
  const float* Wv = (const float*)d_in[7];
  const float* bv = (const float*)d_in[8];
  const float* gamma = (const float*)d_in[9];
  const float* beta  = (const float*)d_in[10];
  float* out = (float*)d_out;

  char* ws = (char*)d_ws;
  unsigned short* Qb = (unsigned short*)(ws);                     // 8 MiB
  unsigned short* Kb = (unsigned short*)(ws + 8 * 1024 * 1024);   // 8 MiB
  unsigned short* Vt = (unsigned short*)(ws + 16 * 1024 * 1024);  // 8 MiB
  unsigned short* Wt = (unsigned short*)(ws + 24 * 1024 * 1024);  // 1.5 MiB
  unsigned short* Xbv = (unsigned short*)(ws + 26 * 1024 * 1024); // 8 MiB
  // O1 overlays Wt+Xbv (both dead after proj); written only by attn (after
  // proj in stream order).
  float* O1 = (float*)(ws + 24 * 1024 * 1024);                    // 16 MiB
  float* qmask = (float*)(ws + 40 * 1024 * 1024);                 // 32 KiB
  float* kbias = qmask + 8192;                                    // 32 KiB
  float* l0 = kbias + 8192;                                       // 256 KiB
  float* l1 = l0 + 65536;                                         // 256 KiB

  // Xb for queries/keys staged in d_out (16 MiB, dead until attn writes O0)
  unsigned short* Xbq = (unsigned short*)d_out;
  unsigned short* Xbk = Xbq + 4194304;
  float* O0 = (float*)d_out;

  prep_kernel<<<6336, 256, 0, stream>>>(queries, keys, values, Wq, Wk, Wv,
                                        Xbq, Xbk, Xbv, Wt, qmask, kbias);
  proj_kernel<<<dim3(192, 4), 256, 0, stream>>>(Xbq, Xbk, Xbv, bq, bk, bv,
                                                Wt, Qb, Kb, Vt);
  attn_kernel<<<dim3(32, 16, 2), 256, 0, stream>>>(Qb, Kb, Vt, kbias,
                                                   O0, O1, l0, l1);
  ln_kernel<<<2048, 256, 0, stream>>>(out, O1, l0, l1, qmask, queries,
                                      gamma, beta);
}

// Round 9
// 177.114 us; speedup vs baseline: 2.2769x; 1.0519x over previous
//
#include <hip/hip_runtime.h>

// R16: attn reverted to R12's proven no-split base (50.4us; final-out
// epilogue, cheap ln) + T15-style 2-stage SOFTWARE PIPELINE in the g-loop:
// at iter g issue ldK(g+2), ldV(g+1), and the QK MFMAs for S(g+1) BEFORE
// consuming stage g (exp/pack/l/PV). S(g+1) runs on the MFMA pipe while
// P(g)'s exp/pack runs on VALU/trans -- the QK latency leaves the critical
// path. All stage indices compile-time (full unroll, 2-slot named arrays).
// Hazards checked: kf/km[cs] rewritten at g last read at g-1; vf[ns]
// written at g read at g+1; s-stage ns written at g read at g+1.
// ~150 VGPR under the proven (256,2) cap-256 regime (cap-128 provably
// spills bodies >~100 regs: R8/R9/R13). prep (merged xcvt+wt transpose)
// kept from R15; proj unchanged; ln back to simple in-place form.

typedef __attribute__((ext_vector_type(8))) __bf16 bf16x8;
typedef __attribute__((ext_vector_type(4))) float f32x4;

#if __has_builtin(__builtin_amdgcn_exp2f)
#define EXP2F __builtin_amdgcn_exp2f
#else
#define EXP2F exp2f
#endif

#define QSCALE (0.125f * 1.4426950408889634f)  // fold /sqrt(64) and ln->log2

__device__ __forceinline__ unsigned short f2bf(float f) {
  return __builtin_bit_cast(unsigned short, (__bf16)f);
}
__device__ __forceinline__ unsigned pk2(float a, float b) {
  return (unsigned)f2bf(a) | ((unsigned)f2bf(b) << 16);
}
__device__ __forceinline__ f32x4 mfma16(bf16x8 a, bf16x8 b, f32x4 c) {
  return __builtin_amdgcn_mfma_f32_16x16x32_bf16(a, b, c, 0, 0, 0);
}
__device__ __forceinline__ bf16x8 ld_bf8(const unsigned short* p) {
  return *(const bf16x8*)p;
}
// async global->LDS, 16 B per lane; LDS dst is wave-uniform base + lane*16
__device__ __forceinline__ void g2l16(const void* g, void* l) {
  __builtin_amdgcn_global_load_lds(
      (const __attribute__((address_space(1))) void*)g,
      (__attribute__((address_space(3))) void*)l, 16, 0, 0);
}

// ---------------------------------------------------------------------------
// Kernel 1: prep = xcvt (blocks 0..6143) + wt LDS-transpose (blocks 6144+).
// xcvt: X fp32->bf16 + qmask (0/1) / kbias (0/-1e30) from exact fp32 sums.
// wt: 64x64 tiles of W read coalesced, transposed via padded LDS, written
// as bf16 Wt[z][n][k] coalesced in k.
// ---------------------------------------------------------------------------
__global__ __launch_bounds__(256) void prep_kernel(
    const float* __restrict__ Xq, const float* __restrict__ Xk,
    const float* __restrict__ Xv, const float* __restrict__ Wq,
    const float* __restrict__ Wk, const float* __restrict__ Wv,
    unsigned short* __restrict__ Xbq, unsigned short* __restrict__ Xbk,
    unsigned short* __restrict__ Xbv, unsigned short* __restrict__ Wt,
    float* __restrict__ qmask, float* __restrict__ kbias) {
  __shared__ float T[64][65];
  int tid = threadIdx.x;
  if (blockIdx.x < 6144) {
    int row = blockIdx.x * 4 + (tid >> 6);
    int lane = tid & 63;
    int z = row >> 13;
    int r = row & 8191;
    const float* X = (z == 0) ? Xq : ((z == 1) ? Xk : Xv);
    unsigned short* Xb = (z == 0) ? Xbq : ((z == 1) ? Xbk : Xbv);
    const float* p = X + r * 512 + lane * 8;
    f32x4 lo = *(const f32x4*)p;
    f32x4 hi = *(const f32x4*)(p + 4);
    *(uint4*)(Xb + r * 512 + lane * 8) =
        make_uint4(pk2(lo[0], lo[1]), pk2(lo[2], lo[3]), pk2(hi[0], hi[1]),
                   pk2(hi[2], hi[3]));
    if (z < 2) {
      float s = lo[0] + lo[1] + lo[2] + lo[3] + hi[0] + hi[1] + hi[2] + hi[3];
#pragma unroll
      for (int off = 1; off < 64; off <<= 1) s += __shfl_xor(s, off);
      if (lane == 0) {
        if (z == 0)
          qmask[r] = (s == 0.f) ? 0.f : 1.f;
        else
          kbias[r] = (s == 0.f) ? -1.0e30f : 0.f;
      }
    }
  } else {
    int bid = blockIdx.x - 6144;  // 0..191
    int z = bid >> 6;
    int t = bid & 63;
    int r0 = (t >> 3) * 64;  // k-tile base (W row)
    int c0 = (t & 7) * 64;   // n-tile base (W col)
    const float* W = (z == 0) ? Wq : ((z == 1) ? Wk : Wv);
    int tr = tid >> 4, tc = tid & 15;
#pragma unroll
    for (int j = 0; j < 4; ++j) {
      int row = r0 + tr + j * 16;
      float4 v = *(const float4*)&W[row * 512 + c0 + tc * 4];
      T[tc * 4 + 0][tr + j * 16] = v.x;
      T[tc * 4 + 1][tr + j * 16] = v.y;
      T[tc * 4 + 2][tr + j * 16] = v.z;
      T[tc * 4 + 3][tr + j * 16] = v.w;
    }
    __syncthreads();
    unsigned short* Wz = Wt + z * 262144;
#pragma unroll
    for (int j = 0; j < 4; ++j) {
      int nl = tr + j * 16;  // local n (W col)
      int kl = tc * 4;       // local k
      float a0 = T[nl][kl], a1 = T[nl][kl + 1];
      float a2 = T[nl][kl + 2], a3 = T[nl][kl + 3];
      *(uint2*)(Wz + (c0 + nl) * 512 + r0 + kl) =
          make_uint2(pk2(a0, a1), pk2(a2, a3));
    }
  }
}

// ---------------------------------------------------------------------------
// Kernel 2: QKV projection, pure-bf16 double-buffered GEMM, ONE barrier per
// K-step. A and B staged [128][32] shorts with source-side XOR swizzle.
// Grid (192 m-blocks, 4 n-blocks); z = m-block/64. Tile 128x128, BK=32.
// V stored transposed with the permuted intra-32-key order
// (pos = quad*8 + sub*4 + r), matching attn's P register-repack k-order.
// ---------------------------------------------------------------------------
__global__ __launch_bounds__(256, 3) void proj_kernel(
    const unsigned short* __restrict__ Xbq, const unsigned short* __restrict__ Xbk,
    const unsigned short* __restrict__ Xbv, const float* __restrict__ bq,
    const float* __restrict__ bk, const float* __restrict__ bv,
    const unsigned short* __restrict__ Wt, unsigned short* __restrict__ Qb,
    unsigned short* __restrict__ Kb, unsigned short* __restrict__ Vt) {
  __shared__ unsigned short Asm[2][128][32];
  __shared__ unsigned short Bsm[2][128][32];

  int tid = threadIdx.x;
  int m0g = blockIdx.x * 128;
  int z = m0g >> 13;
  int m0 = m0g & 8191;
  int n0 = blockIdx.y * 128;
  const unsigned short* Xb = (z == 0) ? Xbq : ((z == 1) ? Xbk : Xbv);
  const float* bias = (z == 0) ? bq : ((z == 1) ? bk : bv);
  const unsigned short* Wz = Wt + z * 262144;

  int w = tid >> 6, lane = tid & 63;
  int wm = w >> 1, wn = w & 1;
  int mrow = lane & 15, quad = lane >> 4;

  int srow = tid >> 2, sslot = tid & 3;
  int sxs = sslot ^ ((srow >> 1) & 3);
  const unsigned short* gA = Xb + (m0 + srow) * 512 + sxs * 8;
  const unsigned short* gB = Wz + (n0 + srow) * 512 + sxs * 8;
  char* lA = (char*)&Asm[0][0][0] + tid * 16;
  char* lB = (char*)&Bsm[0][0][0] + tid * 16;

  int rs = (quad ^ ((mrow >> 1) & 3)) * 8;

  f32x4 zero = {0.f, 0.f, 0.f, 0.f};
  f32x4 acc[4][4];
#pragma unroll
  for (int i = 0; i < 4; ++i)
#pragma unroll
    for (int j = 0; j < 4; ++j) acc[i][j] = zero;

  g2l16(gA, lA);
  g2l16(gA + 64 * 512, lA + 4096);
  g2l16(gB, lB);
  g2l16(gB + 64 * 512, lB + 4096);
  __syncthreads();

  for (int kc = 0; kc < 16; ++kc) {
    int cur = kc & 1;
    if (kc < 15) {
      int ko = (kc + 1) * 32;
      int nb = cur ^ 1;
      g2l16(gA + ko, lA + nb * 8192);
      g2l16(gA + ko + 64 * 512, lA + nb * 8192 + 4096);
      g2l16(gB + ko, lB + nb * 8192);
      g2l16(gB + ko + 64 * 512, lB + nb * 8192 + 4096);
    }
    bf16x8 af[4], bfr[4];
#pragma unroll
    for (int mt = 0; mt < 4; ++mt)
      af[mt] = ld_bf8(&Asm[cur][wm * 64 + mt * 16 + mrow][rs]);
#pragma unroll
    for (int nt = 0; nt < 4; ++nt)
      bfr[nt] = ld_bf8(&Bsm[cur][wn * 64 + nt * 16 + mrow][rs]);
#pragma unroll
    for (int mt = 0; mt < 4; ++mt)
#pragma unroll
      for (int nt = 0; nt < 4; ++nt)
        acc[mt][nt] = mfma16(af[mt], bfr[nt], acc[mt][nt]);
    __syncthreads();
  }

  if (z < 2) {
    unsigned short* dst = (z == 0) ? Qb : Kb;
    float sc = (z == 0) ? QSCALE : 1.0f;
#pragma unroll
    for (int nt = 0; nt < 4; ++nt) {
      int n = n0 + wn * 64 + nt * 16 + mrow;
      float bv_ = bias[n];
#pragma unroll
      for (int mt = 0; mt < 4; ++mt) {
        int m = m0 + wm * 64 + mt * 16 + quad * 4;
#pragma unroll
        for (int r = 0; r < 4; ++r) {
          float v = fmaxf(acc[mt][nt][r] + bv_, 0.f) * sc;
          dst[(m + r) * 512 + n] = f2bf(v);
        }
      }
    }
  } else {
    // V: permuted-transposed store (pos = quad*8 + (mt&1)*4 + r in 32-t group)
#pragma unroll
    for (int nt = 0; nt < 4; ++nt) {
      int n = n0 + wn * 64 + nt * 16 + mrow;
      int hh = n >> 6, jj = n & 63;
      float bv_ = bias[n];
#pragma unroll
      for (int mt = 0; mt < 4; ++mt) {
        int grow = m0 + wm * 64 + mt * 16 + quad * 4;
        int bb = grow >> 11, tl = grow & 2047;
        int pos = (tl & ~31) + quad * 8 + (mt & 1) * 4;
        float p0 = fmaxf(acc[mt][nt][0] + bv_, 0.f);
        float p1 = fmaxf(acc[mt][nt][1] + bv_, 0.f);
        float p2 = fmaxf(acc[mt][nt][2] + bv_, 0.f);
        float p3 = fmaxf(acc[mt][nt][3] + bv_, 0.f);
        *(uint2*)(Vt + ((hh * 4 + bb) * 64 + jj) * 2048 + pos) =
            make_uint2(pk2(p0, p1), pk2(p2, p3));
      }
    }
  }
}

// ---------------------------------------------------------------------------
// Kernel 3: attention, 4-wave q-owner, w_q=32, SOFTWARE-PIPELINED g-loop.
// Grid (hb=32, qt=16); 256 thr; wave w owns q rows q0+w*32..+31 over all
// 2048 keys (16 chunks of 128). K+V LDS dbuf 64 KB, XOR-swizzled staging,
// conflict-free b128 reads. Per chunk: 4 g-groups of 32 keys, pipelined:
// iter g issues ldK(g+2) / ldV(g+1) / S(g+1) QK-MFMAs BEFORE consuming
// stage g (exp/pack, l-MFMA vs ones, PV). QK seeded with kbias. Epilogue:
// per-lane final write (qmask/l + queries residual).
// ---------------------------------------------------------------------------
__global__ __launch_bounds__(256, 2) void attn_kernel(
    const unsigned short* __restrict__ Qb, const unsigned short* __restrict__ Kb,
    const unsigned short* __restrict__ Vt, const float* __restrict__ qmask,
    const float* __restrict__ kbias, const float* __restrict__ queries,
    float* __restrict__ out) {
  __shared__ char smem[65536];
  unsigned short* KsmS = (unsigned short*)smem;            // [2][8192] shorts
  unsigned short* VsmS = (unsigned short*)(smem + 32768);  // [2][8192] shorts

  int hb = blockIdx.x;
  int qt = blockIdx.y;
  int h = hb >> 2, b = hb & 3;
  int q0 = qt * 128;
  int tid = threadIdx.x;
  int w = tid >> 6, lane = tid & 63;
  int mrow = lane & 15, quad = lane >> 4;
  int mlow = mrow & 7;

  // staging sources (XOR-swizzled slot->chunk), 256-thr:
  const unsigned short* gK =
      Kb + (b * 2048 + (tid >> 3)) * 512 + h * 64 + (((tid & 7) ^ ((tid >> 3) & 7)) * 8);
  const unsigned short* gV =
      Vt + (hb * 64 + (tid >> 4)) * 2048 + (((tid & 15) ^ ((tid >> 4) & 15)) * 8);

  // Q B-frags for this wave's 32 q rows: [qn][k-half]
  bf16x8 qf[2][2];
  {
    const unsigned short* qp =
        Qb + (b * 2048 + q0 + w * 32 + mrow) * 512 + h * 64 + quad * 8;
    qf[0][0] = ld_bf8(qp);
    qf[0][1] = ld_bf8(qp + 32);
    qf[1][0] = ld_bf8(qp + 8192);
    qf[1][1] = ld_bf8(qp + 8192 + 32);
  }

  bf16x8 onev;
#pragma unroll
  for (int i = 0; i < 8; ++i) onev[i] = (__bf16)1.0f;

  f32x4 zero = {0.f, 0.f, 0.f, 0.f};
  f32x4 oacc[4][2];  // [dt][qn]: col=dh dt*16+mrow, row=q quad*4+r
#pragma unroll
  for (int i = 0; i < 4; ++i)
#pragma unroll
    for (int j = 0; j < 2; ++j) oacc[i][j] = zero;
  f32x4 lacc[2] = {zero, zero};  // l[q], replicated over cols

  const float* kmB = kbias + b * 2048 + quad * 4;

  // preload chunk 0 into buf 0
#pragma unroll
  for (int j = 0; j < 4; ++j) {
    g2l16(gK + j * 32 * 512, &KsmS[j * 2048 + tid * 8]);
    g2l16(gV + j * 16 * 2048, &VsmS[j * 2048 + tid * 8]);
  }

  for (int it = 0; it < 16; ++it) {
    int bi = it & 1;
    int kb = it * 128;
    __syncthreads();  // drains staging DMA; buf bi ready

    if (it < 15) {
      int nb = 1 - bi;
      int nkb = kb + 128;
#pragma unroll
      for (int j = 0; j < 4; ++j) {
        g2l16(gK + (nkb + j * 32) * 512, &KsmS[nb * 8192 + j * 2048 + tid * 8]);
        g2l16(gV + nkb + j * 16 * 2048, &VsmS[nb * 8192 + j * 2048 + tid * 8]);
      }
    }

    const unsigned short* Kc = KsmS + bi * 8192;
    const unsigned short* Vc = VsmS + bi * 8192;

    // 2-slot pipelined state (all indices compile-time under full unroll)
    bf16x8 kf[2][4], vf[2][4];
    f32x4 km[2][2], sA[2][2], sB[2][2];

    auto ldK = [&](int gi, int sl) {
      km[sl][0] = *(const f32x4*)(kmB + kb + gi * 32);
      km[sl][1] = *(const f32x4*)(kmB + kb + gi * 32 + 16);
      kf[sl][0] = ld_bf8(&Kc[(gi * 32 + mrow) * 64 + (quad ^ mlow) * 8]);
      kf[sl][1] = ld_bf8(&Kc[(gi * 32 + mrow) * 64 + ((4 + quad) ^ mlow) * 8]);
      kf[sl][2] = ld_bf8(&Kc[(gi * 32 + 16 + mrow) * 64 + (quad ^ mlow) * 8]);
      kf[sl][3] = ld_bf8(&Kc[(gi * 32 + 16 + mrow) * 64 + ((4 + quad) ^ mlow) * 8]);
    };
    auto ldV = [&](int gi, int sl) {
#pragma unroll
      for (int dt = 0; dt < 4; ++dt)
        vf[sl][dt] =
            ld_bf8(&Vc[(dt * 16 + mrow) * 128 + ((gi * 4 + quad) ^ mrow) * 8]);
    };
    auto doS = [&](int sl) {  // S from kf[sl]/km[sl] into stage sl
#pragma unroll
      for (int qn = 0; qn < 2; ++qn) {
        f32x4 t0 = mfma16(kf[sl][0], qf[qn][0], km[sl][0]);
        sA[sl][qn] = mfma16(kf[sl][1], qf[qn][1], t0);
        f32x4 t1 = mfma16(kf[sl][2], qf[qn][0], km[sl][1]);
        sB[sl][qn] = mfma16(kf[sl][3], qf[qn][1], t1);
      }
    };

    ldK(0, 0);
    ldV(0, 0);
    ldK(1, 1);
    doS(0);  // S(0) into stage 0
#pragma unroll
    for (int g = 0; g < 4; ++g) {
      int cs = g & 1, ns = cs ^ 1;
      if (g < 2) ldK(g + 2, cs);   // kf/km[cs] last read at iter g-1
      if (g < 3) ldV(g + 1, ns);   // vf[ns] read at iter g+1
      __builtin_amdgcn_s_setprio(1);
      if (g < 3) doS(ns);          // S(g+1): MFMA pipe, overlaps exp below
      // consume stage cs: exp/pack -> l-MFMA -> PV
#pragma unroll
      for (int qn = 0; qn < 2; ++qn) {
        f32x4 p0, p1;
#pragma unroll
        for (int r = 0; r < 4; ++r) {
          p0[r] = EXP2F(sA[cs][qn][r]);
          p1[r] = EXP2F(sB[cs][qn][r]);
        }
        bf16x8 pf = __builtin_bit_cast(
            bf16x8, make_uint4(pk2(p0[0], p0[1]), pk2(p0[2], p0[3]),
                               pk2(p1[0], p1[1]), pk2(p1[2], p1[3])));
        lacc[qn] = mfma16(pf, onev, lacc[qn]);
#pragma unroll
        for (int dt = 0; dt < 4; ++dt)
          oacc[dt][qn] = mfma16(pf, vf[cs][dt], oacc[dt][qn]);
      }
      __builtin_amdgcn_s_setprio(0);
    }
  }

  // --- epilogue: pure per-lane (lacc[qn][r] is l for row qn*16+quad*4+r)
#pragma unroll
  for (int qn = 0; qn < 2; ++qn) {
#pragma unroll
    for (int r = 0; r < 4; ++r) {
      int qg = b * 2048 + q0 + w * 32 + qn * 16 + quad * 4 + r;
      float inv = qmask[qg] / lacc[qn][r];
      const float* qsrc = queries + qg * 512 + h * 64 + mrow;
      float* od = out + qg * 512 + h * 64 + mrow;
#pragma unroll
      for (int dt = 0; dt < 4; ++dt)
        od[dt * 16] = oacc[dt][qn][r] * inv + qsrc[dt * 16];
    }
  }
}

// ---------------------------------------------------------------------------
// Kernel 4: LayerNorm (unbiased std, eps added to std), in-place on d_out.
// ---------------------------------------------------------------------------
__global__ __launch_bounds__(256) void ln_kernel(float* __restrict__ out,
                                                 const float* __restrict__ gamma,
                                                 const float* __restrict__ beta) {
  int row = blockIdx.x * 4 + (threadIdx.x >> 6);
  int lane = threadIdx.x & 63;
  float* p = out + row * 512;
  float4 v1 = ((const float4*)p)[lane];
  float4 v2 = ((const float4*)p)[64 + lane];
  float s = v1.x + v1.y + v1.z + v1.w + v2.x + v2.y + v2.z + v2.w;
  float sq = v1.x * v1.x + v1.y * v1.y + v1.z * v1.z + v1.w * v1.w +
             v2.x * v2.x + v2.y * v2.y + v2.z * v2.z + v2.w * v2.w;
#pragma unroll
  for (int off = 32; off > 0; off >>= 1) {
    s += __shfl_xor(s, off);
    sq += __shfl_xor(sq, off);
  }
  float mean = s * (1.f / 512.f);
  float var = fmaxf((sq - 512.f * mean * mean) * (1.f / 511.f), 0.f);
  float inv = 1.f / (sqrtf(var) + 1e-8f);
  float4 g1 = ((const float4*)gamma)[lane];
  float4 g2 = ((const float4*)gamma)[64 + lane];
  float4 b1 = ((const float4*)beta)[lane];
  float4 b2 = ((const float4*)beta)[64 + lane];
  v1.x = g1.x * (v1.x - mean) * inv + b1.x;
  v1.y = g1.y * (v1.y - mean) * inv + b1.y;
  v1.z = g1.z * (v1.z - mean) * inv + b1.z;
  v1.w = g1.w * (v1.w - mean) * inv + b1.w;
  v2.x = g2.x * (v2.x - mean) * inv + b2.x;
  v2.y = g2.y * (v2.y - mean) * inv + b2.y;
  v2.z = g2.z * (v2.z - mean) * inv + b2.z;
  v2.w = g2.w * (v2.w - mean) * inv + b2.w;
  ((float4*)p)[lane] = v1;
  ((float4*)p)[64 + lane] = v2;
}

// ---------------------------------------------------------------------------
extern "C" void kernel_launch(void* const* d_in, const int* in_sizes, int n_in,
                              void* d_out, int out_size, void* d_ws, size_t ws_size,
                              hipStream_t stream) {
  (void)in_sizes; (void)n_in; (void)out_size; (void)ws_size;
  const float* queries = (const float*)d_in[0];
  const float* keys    = (const float*)d_in[1];
  const float* values  = (const float*)d_in[2];
  const float* Wq = (const float*)d_in[3];
  const float* bq = (const float*)d_in[4];
  const float* Wk = (const float*)d_in[5];
  const float* bk = (const float*)d_in[6];
  const float* Wv = (const float*)d_in[7];
  const float* bv = (const float*)d_in[8];
  const float* gamma = (const float*)d_in[9];
  const float* beta  = (const float*)d_in[10];
  float* out = (float*)d_out;

  char* ws = (char*)d_ws;
  unsigned short* Qb = (unsigned short*)(ws);                     // 8 MiB
  unsigned short* Kb = (unsigned short*)(ws + 8 * 1024 * 1024);   // 8 MiB
  unsigned short* Vt = (unsigned short*)(ws + 16 * 1024 * 1024);  // 8 MiB
  unsigned short* Wt = (unsigned short*)(ws + 24 * 1024 * 1024);  // 1.5 MiB
  unsigned short* Xbv = (unsigned short*)(ws + 26 * 1024 * 1024); // 8 MiB
  float* qmask = (float*)(ws + 34 * 1024 * 1024);
  float* kbias = qmask + 8192;

  // Xb for queries/keys staged in d_out (16 MiB, dead until attn writes it)
  unsigned short* Xbq = (unsigned short*)d_out;
  unsigned short* Xbk = Xbq + 4194304;

  prep_kernel<<<6336, 256, 0, stream>>>(queries, keys, values, Wq, Wk, Wv,
                                        Xbq, Xbk, Xbv, Wt, qmask, kbias);
  proj_kernel<<<dim3(192, 4), 256, 0, stream>>>(Xbq, Xbk, Xbv, bq, bk, bv,
                                                Wt, Qb, Kb, Vt);
  attn_kernel<<<dim3(32, 16), 256, 0, stream>>>(Qb, Kb, Vt, qmask, kbias,
                                                queries, out);
  ln_kernel<<<2048, 256, 0, stream>>>(out, gamma, beta);
}